// Round 8
// baseline (822.671 us; speedup 1.0000x reference)
//
#include <hip/hip_runtime.h>
#include <hip/hip_bf16.h>

typedef unsigned short u16;
typedef unsigned int   u32;
typedef __bf16 bf16x8 __attribute__((ext_vector_type(8)));
typedef float  f32x4  __attribute__((ext_vector_type(4)));

#define NB 4
#define T_ 2048
#define D_ 1024
#define H_ 16
#define DH 64
#define M_ (NB * T_)   // 8192 rows
#define PSTR 72        // wconv LDS stride
#define ASTR 68        // attn LDS stride (34 dwords ≡ 2 mod 32: b128 conflict-free)

__device__ __forceinline__ float bf2f(u16 u) {
    union { u32 i; float f; } v; v.i = ((u32)u) << 16; return v.f;
}
__device__ __forceinline__ u16 f2bf(float f) {
    union { float fl; u32 i; } v; v.fl = f;
    u32 r = v.i + 0x7fff + ((v.i >> 16) & 1);
    return (u16)(r >> 16);
}

// async global->LDS, 16B per lane; LDS dest = wave-uniform base + lane*16
__device__ __forceinline__ void gld16(const u16* g, u16* l) {
    __builtin_amdgcn_global_load_lds(
        (const __attribute__((address_space(1))) void*)g,
        (__attribute__((address_space(3))) void*)l,
        16, 0, 0);
}

// ---------------------------------------------------------- dtype detector
__device__ __forceinline__ int detect_f32(const u16* p) {
    int weird = 0;
    const int lane = threadIdx.x & 63;
    #pragma unroll
    for (int i = 0; i < 4; ++i) {
        const u16 u = p[lane * 4 + i];
        const int e = (u >> 7) & 0xFF;
        weird += (e == 0xFF || (e >= 0x01 && e <= 0x3F) || (e >= 0xC0 && e <= 0xFE));
    }
    #pragma unroll
    for (int off = 32; off; off >>= 1) weird += __shfl_xor(weird, off);
    return weird >= 16;
}

__device__ __forceinline__ int read_len(const void* raw, int b) {
    const int* a32 = (const int*)raw;
    bool ok32 = true;
    #pragma unroll
    for (int i = 0; i < NB; ++i) {
        const int v = a32[i];
        if (v < 1 || v > T_) ok32 = false;
    }
    int v = ok32 ? a32[b] : (int)((const long long*)raw)[b];
    return min(max(v, 1), T_);
}

// ---------------------------------------------------------------- LayerNorm
__global__ __launch_bounds__(256) void ln_kernel(const void* __restrict__ xraw,
                                                 const void* __restrict__ graw,
                                                 const void* __restrict__ braw,
                                                 u16* __restrict__ h) {
    const int row = blockIdx.x;
    const int tid = threadIdx.x;
    const int isf = detect_f32((const u16*)xraw);

    float xv[4];
    if (isf) {
        const float* xr = (const float*)xraw + (size_t)row * D_;
        *(float4*)xv = *(const float4*)&xr[tid * 4];
    } else {
        const u16* xr = (const u16*)xraw + (size_t)row * D_;
        u16 loc[4] __attribute__((aligned(8)));
        *(uint2*)loc = *(const uint2*)&xr[tid * 4];
        #pragma unroll
        for (int i = 0; i < 4; ++i) xv[i] = bf2f(loc[i]);
    }

    float s = xv[0] + xv[1] + xv[2] + xv[3];
    float q = xv[0]*xv[0] + xv[1]*xv[1] + xv[2]*xv[2] + xv[3]*xv[3];

    #pragma unroll
    for (int off = 32; off; off >>= 1) {
        s += __shfl_xor(s, off);
        q += __shfl_xor(q, off);
    }
    __shared__ float red[8];
    const int wave = tid >> 6, lane = tid & 63;
    if (lane == 0) { red[wave] = s; red[4 + wave] = q; }
    __syncthreads();
    s = red[0] + red[1] + red[2] + red[3];
    q = red[4] + red[5] + red[6] + red[7];

    const float mean = s * (1.0f / D_);
    const float var  = q * (1.0f / D_) - mean * mean;
    const float rs   = rsqrtf(var + 1e-5f);

    u16 o[4] __attribute__((aligned(8)));
    #pragma unroll
    for (int i = 0; i < 4; ++i) {
        const int c = tid * 4 + i;
        const float gv = isf ? ((const float*)graw)[c] : bf2f(((const u16*)graw)[c]);
        const float bv = isf ? ((const float*)braw)[c] : bf2f(((const u16*)braw)[c]);
        o[i] = f2bf((xv[i] - mean) * rs * gv + bv);
    }
    *(uint2*)&h[(size_t)row * D_ + tid * 4] = *(uint2*)o;
}

// ------------------------------------------------- weight transpose+convert
__global__ __launch_bounds__(256) void wconv_kernel(const void* __restrict__ Wraw,
                                                    u16* __restrict__ Wt) {
    __shared__ u16 tile[64][PSTR];
    const int isf = detect_f32((const u16*)Wraw);
    const int n0 = blockIdx.x * 64;
    const int k0 = blockIdx.y * 64;
    const int tid = threadIdx.x;
    const int tr  = tid >> 2;
    const int tc  = (tid & 3) * 16;

    if (isf) {
        const float* W = (const float*)Wraw;
        #pragma unroll
        for (int i = 0; i < 16; ++i)
            tile[tc + i][tr] = f2bf(W[(size_t)(k0 + tr) * D_ + n0 + tc + i]);
    } else {
        const u16* W = (const u16*)Wraw;
        #pragma unroll
        for (int i = 0; i < 16; ++i)
            tile[tc + i][tr] = W[(size_t)(k0 + tr) * D_ + n0 + tc + i];
    }
    __syncthreads();
    *(uint4*)&Wt[(size_t)(n0 + tr) * D_ + k0 + tc]     = *(uint4*)&tile[tr][tc];
    *(uint4*)&Wt[(size_t)(n0 + tr) * D_ + k0 + tc + 8] = *(uint4*)&tile[tr][tc + 8];
}

// --------------------------------------------------------- fused QKV GEMM
// N=3072 (Wq|Wk|Wv transposed rows contiguous). 128x128 tiles, BK=32,
// global_load_lds staging, 4 waves 2x2, 4x4 mfma each.
// wi = n/1024 selects weight: 0,1 -> RoPE + (N,H,T,DH) scatter; 2 -> V^T.
__global__ __launch_bounds__(256) void gemmqkv_kernel(const u16* __restrict__ A,
                                                      const u16* __restrict__ Bt3,
                                                      const void* __restrict__ bqraw,
                                                      const void* __restrict__ bkraw,
                                                      const void* __restrict__ bvraw,
                                                      u16* __restrict__ qkv) {
    __shared__ __align__(16) u16 As[128 * 32];
    __shared__ __align__(16) u16 Bs[128 * 32];

    const int tid   = threadIdx.x;
    const int nglob = blockIdx.x * 128;          // 0..3071
    const int wi    = nglob >> 10;               // weight index 0..2
    const int nloc  = nglob & 1023;              // n-tile base within weight
    const int mtile = blockIdx.y * 128;
    const int wv    = tid >> 6;
    const int ln    = tid & 63;
    const int quad  = ln >> 4;
    const int lr    = ln & 15;
    const int wy    = wv >> 1;
    const int wx    = wv & 1;

    const void* braw = (wi == 0) ? bqraw : (wi == 1) ? bkraw : bvraw;
    const int isfb = detect_f32((const u16*)braw);
    u16* out = qkv + (size_t)wi * M_ * D_;

    f32x4 acc[4][4];
    #pragma unroll
    for (int mt = 0; mt < 4; ++mt)
        #pragma unroll
        for (int nt = 0; nt < 4; ++nt)
            acc[mt][nt] = (f32x4){0.f, 0.f, 0.f, 0.f};

    const int srow = wv * 32 + (ln >> 2);
    const int skb  = (ln & 3) * 8;
    const u16* gA0 = A   + (size_t)(mtile + srow) * D_ + skb;
    const u16* gA1 = gA0 + (size_t)16 * D_;
    const u16* gB0 = Bt3 + (size_t)(nglob + srow) * D_ + skb;
    const u16* gB1 = gB0 + (size_t)16 * D_;
    u16* lA0 = As + wv * 1024;
    u16* lA1 = lA0 + 512;
    u16* lB0 = Bs + wv * 1024;
    u16* lB1 = lB0 + 512;

    for (int k0 = 0; k0 < D_; k0 += 32) {
        gld16(gA0 + k0, lA0);
        gld16(gA1 + k0, lA1);
        gld16(gB0 + k0, lB0);
        gld16(gB1 + k0, lB1);
        __syncthreads();

        bf16x8 af[4], bfr[4];
        #pragma unroll
        for (int mt = 0; mt < 4; ++mt)
            af[mt] = *(const bf16x8*)&As[(wy * 64 + mt * 16 + lr) * 32 + quad * 8];
        #pragma unroll
        for (int nt = 0; nt < 4; ++nt)
            bfr[nt] = *(const bf16x8*)&Bs[(wx * 64 + nt * 16 + lr) * 32 + quad * 8];
        #pragma unroll
        for (int mt = 0; mt < 4; ++mt)
            #pragma unroll
            for (int nt = 0; nt < 4; ++nt)
                acc[mt][nt] = __builtin_amdgcn_mfma_f32_16x16x32_bf16(af[mt], bfr[nt], acc[mt][nt], 0, 0, 0);
        __syncthreads();
    }

    #pragma unroll
    for (int mt = 0; mt < 4; ++mt) {
        #pragma unroll
        for (int nt = 0; nt < 4; ++nt) {
            const int ncol = nloc + wx * 64 + nt * 16 + lr;   // within weight
            const float bv = isfb ? ((const float*)braw)[ncol]
                                  : bf2f(((const u16*)braw)[ncol]);
            #pragma unroll
            for (int r = 0; r < 4; ++r) {
                const int mrow = mtile + wy * 64 + mt * 16 + quad * 4 + r;
                float v = acc[mt][nt][r] + bv;
                const int d  = ncol & (DH - 1);
                const int hh = ncol >> 6;
                const int t  = mrow & (T_ - 1);
                const int bb = mrow >> 11;
                if (wi < 2) {
                    const float other = __shfl_xor(v, 1);
                    const int i = d >> 1;
                    const float inv = exp2f(-(float)i * 0.41524101186092f);
                    const float ang = (float)t * inv;
                    const float cv = cosf(ang), sv = sinf(ang);
                    v = (d & 1) ? (other * sv + v * cv) : (v * cv - other * sv);
                    out[(((size_t)(bb * H_ + hh) * T_) + t) * DH + d] = f2bf(v);
                } else {
                    out[(((size_t)(bb * H_ + hh) * DH) + d) * T_ + t] = f2bf(v);
                }
            }
        }
    }
}

// --------------------------------------------------------- GEMM 128x128 (out proj)
__global__ __launch_bounds__(256) void gemm128_kernel(const u16* __restrict__ A,
                                                      const u16* __restrict__ Bt,
                                                      const void* __restrict__ Braw,
                                                      const void* __restrict__ biasraw,
                                                      void* __restrict__ out) {
    __shared__ __align__(16) u16 As[128 * 32];
    __shared__ __align__(16) u16 Bs[128 * 32];

    const int tid   = threadIdx.x;
    const int ntile = blockIdx.x * 128;
    const int mtile = blockIdx.y * 128;
    const int wv    = tid >> 6;
    const int ln    = tid & 63;
    const int quad  = ln >> 4;
    const int lr    = ln & 15;
    const int wy    = wv >> 1;
    const int wx    = wv & 1;

    const int isf  = detect_f32((const u16*)Braw);
    const int isfb = detect_f32((const u16*)biasraw);

    f32x4 acc[4][4];
    #pragma unroll
    for (int mt = 0; mt < 4; ++mt)
        #pragma unroll
        for (int nt = 0; nt < 4; ++nt)
            acc[mt][nt] = (f32x4){0.f, 0.f, 0.f, 0.f};

    const int srow = wv * 32 + (ln >> 2);
    const int skb  = (ln & 3) * 8;
    const u16* gA0 = A  + (size_t)(mtile + srow) * D_ + skb;
    const u16* gA1 = gA0 + (size_t)16 * D_;
    const u16* gB0 = Bt + (size_t)(ntile + srow) * D_ + skb;
    const u16* gB1 = gB0 + (size_t)16 * D_;
    u16* lA0 = As + wv * 1024;
    u16* lA1 = lA0 + 512;
    u16* lB0 = Bs + wv * 1024;
    u16* lB1 = lB0 + 512;

    for (int k0 = 0; k0 < D_; k0 += 32) {
        gld16(gA0 + k0, lA0);
        gld16(gA1 + k0, lA1);
        gld16(gB0 + k0, lB0);
        gld16(gB1 + k0, lB1);
        __syncthreads();

        bf16x8 af[4], bfr[4];
        #pragma unroll
        for (int mt = 0; mt < 4; ++mt)
            af[mt] = *(const bf16x8*)&As[(wy * 64 + mt * 16 + lr) * 32 + quad * 8];
        #pragma unroll
        for (int nt = 0; nt < 4; ++nt)
            bfr[nt] = *(const bf16x8*)&Bs[(wx * 64 + nt * 16 + lr) * 32 + quad * 8];
        #pragma unroll
        for (int mt = 0; mt < 4; ++mt)
            #pragma unroll
            for (int nt = 0; nt < 4; ++nt)
                acc[mt][nt] = __builtin_amdgcn_mfma_f32_16x16x32_bf16(af[mt], bfr[nt], acc[mt][nt], 0, 0, 0);
        __syncthreads();
    }

    #pragma unroll
    for (int mt = 0; mt < 4; ++mt) {
        #pragma unroll
        for (int nt = 0; nt < 4; ++nt) {
            const int ncol = ntile + wx * 64 + nt * 16 + lr;
            const float bv = isfb ? ((const float*)biasraw)[ncol]
                                  : bf2f(((const u16*)biasraw)[ncol]);
            #pragma unroll
            for (int r = 0; r < 4; ++r) {
                const int mrow = mtile + wy * 64 + mt * 16 + quad * 4 + r;
                const float v = acc[mt][nt][r] + bv;
                if (isf) ((float*)out)[(size_t)mrow * D_ + ncol] = v;
                else     ((u16*)out)[(size_t)mrow * D_ + ncol] = f2bf(v);
            }
        }
    }
}

// ---------------------------------------------------------------- attention
// MFMA flash attention, fixed-max softmax. 128 q-rows/block (wave owns 32),
// 64-key tiles. Double-buffered K/V LDS + register prefetch: ONE barrier per
// K-tile; P round-trip is wave-private (no barrier).
__global__ __launch_bounds__(256) void attn_kernel(const u16* __restrict__ Q,
                                                   const u16* __restrict__ K,
                                                   const u16* __restrict__ Vt,
                                                   const void* __restrict__ lensraw,
                                                   u16* __restrict__ ctx) {
    __shared__ __align__(16) u16 Ks [2][64 * ASTR];   // [key][dim]
    __shared__ __align__(16) u16 Vts[2][64 * ASTR];   // [dim][key]
    __shared__ __align__(16) u16 Ps [128 * ASTR];     // Q staging, then P

    const int tid  = threadIdx.x;
    const int wave = tid >> 6;
    const int lane = tid & 63;
    const int quad = lane >> 4;
    const int lr   = lane & 15;
    const int bh   = blockIdx.y;
    const int qs   = (gridDim.x - 1 - blockIdx.x) * 128;   // heavy tiles first
    const int b    = bh >> 4;
    const int hh   = bh & 15;
    const int len  = read_len(lensraw, b);
    const size_t base = (size_t)bh * T_ * DH;

    // stage Q (128x64) into Ps
    {
        const int r0 = tid >> 1;
        const int c0 = (tid & 1) * 32;
        const u16* src = &Q[base + (size_t)(qs + r0) * DH + c0];
        *(uint4*)&Ps[r0 * ASTR + c0]      = *(const uint4*)(src);
        *(uint4*)&Ps[r0 * ASTR + c0 + 8]  = *(const uint4*)(src + 8);
        *(uint4*)&Ps[r0 * ASTR + c0 + 16] = *(const uint4*)(src + 16);
        *(uint4*)&Ps[r0 * ASTR + c0 + 24] = *(const uint4*)(src + 24);
    }

    // K/V prefetch registers (tile staged by 256 threads: 16 elems each array)
    const int sr = tid >> 2;            // 0..63
    const int sc = (tid & 3) * 16;
    uint4 kr0, kr1, vr0, vr1;
    kr0 = *(const uint4*)&K[base + (size_t)sr * DH + sc];
    kr1 = *(const uint4*)&K[base + (size_t)sr * DH + sc + 8];
    vr0 = *(const uint4*)&Vt[base + (size_t)sr * T_ + sc];
    vr1 = *(const uint4*)&Vt[base + (size_t)sr * T_ + sc + 8];
    *(uint4*)&Ks[0][sr * ASTR + sc]      = kr0;
    *(uint4*)&Ks[0][sr * ASTR + sc + 8]  = kr1;
    *(uint4*)&Vts[0][sr * ASTR + sc]     = vr0;
    *(uint4*)&Vts[0][sr * ASTR + sc + 8] = vr1;
    __syncthreads();

    // Q A-frags: wave rows wave*32 .. +31 (two 16-row groups, two k-halves)
    bf16x8 qa[2][2];
    #pragma unroll
    for (int rg = 0; rg < 2; ++rg) {
        qa[rg][0] = *(const bf16x8*)&Ps[(wave * 32 + rg * 16 + lr) * ASTR + quad * 8];
        qa[rg][1] = *(const bf16x8*)&Ps[(wave * 32 + rg * 16 + lr) * ASTR + 32 + quad * 8];
    }

    f32x4 acc[2][4];
    float l_loc[2][4];
    #pragma unroll
    for (int rg = 0; rg < 2; ++rg) {
        #pragma unroll
        for (int nt = 0; nt < 4; ++nt) acc[rg][nt] = (f32x4){0.f, 0.f, 0.f, 0.f};
        #pragma unroll
        for (int r = 0; r < 4; ++r) l_loc[rg][r] = 0.f;
    }

    const int smax = min(qs + 127, len - 1);
    const int ktn  = smax / 64 + 1;

    for (int kt = 0; kt < ktn; ++kt) {
        const int cur  = kt & 1;
        const int ks   = kt * 64;
        const bool more = (kt + 1 < ktn);
        if (more) {   // prefetch next tile into regs (latency hidden by compute)
            const int ksn = ks + 64;
            kr0 = *(const uint4*)&K[base + (size_t)(ksn + sr) * DH + sc];
            kr1 = *(const uint4*)&K[base + (size_t)(ksn + sr) * DH + sc + 8];
            vr0 = *(const uint4*)&Vt[base + (size_t)sr * T_ + ksn + sc];
            vr1 = *(const uint4*)&Vt[base + (size_t)sr * T_ + ksn + sc + 8];
        }

        // QK^T
        f32x4 s[2][4];
        #pragma unroll
        for (int rg = 0; rg < 2; ++rg)
            #pragma unroll
            for (int nt = 0; nt < 4; ++nt) s[rg][nt] = (f32x4){0.f, 0.f, 0.f, 0.f};
        #pragma unroll
        for (int nt = 0; nt < 4; ++nt) {
            bf16x8 kb0 = *(const bf16x8*)&Ks[cur][(nt * 16 + lr) * ASTR + quad * 8];
            bf16x8 kb1 = *(const bf16x8*)&Ks[cur][(nt * 16 + lr) * ASTR + 32 + quad * 8];
            #pragma unroll
            for (int rg = 0; rg < 2; ++rg) {
                s[rg][nt] = __builtin_amdgcn_mfma_f32_16x16x32_bf16(qa[rg][0], kb0, s[rg][nt], 0, 0, 0);
                s[rg][nt] = __builtin_amdgcn_mfma_f32_16x16x32_bf16(qa[rg][1], kb1, s[rg][nt], 0, 0, 0);
            }
        }

        // fixed-max softmax: p = exp(-60/(z+1)), z = exp(s/120)
        #pragma unroll
        for (int rg = 0; rg < 2; ++rg) {
            #pragma unroll
            for (int r = 0; r < 4; ++r) {
                const int trow = qs + wave * 32 + rg * 16 + quad * 4 + r;
                #pragma unroll
                for (int nt = 0; nt < 4; ++nt) {
                    const float z = __expf(s[rg][nt][r] * (1.0f / 120.0f));
                    float p = __expf(-60.0f * __builtin_amdgcn_rcpf(z + 1.0f));
                    const int col = ks + nt * 16 + lr;
                    p = (col > trow || col >= len) ? 0.f : p;
                    l_loc[rg][r] += p;
                    Ps[(wave * 32 + rg * 16 + quad * 4 + r) * ASTR + nt * 16 + lr] = f2bf(p);
                }
            }
        }
        // P slice is wave-private: within-wave lgkmcnt ordering suffices.

        // PV
        bf16x8 pa[2][2];
        #pragma unroll
        for (int rg = 0; rg < 2; ++rg) {
            pa[rg][0] = *(const bf16x8*)&Ps[(wave * 32 + rg * 16 + lr) * ASTR + quad * 8];
            pa[rg][1] = *(const bf16x8*)&Ps[(wave * 32 + rg * 16 + lr) * ASTR + 32 + quad * 8];
        }
        #pragma unroll
        for (int nt = 0; nt < 4; ++nt) {
            bf16x8 vb0 = *(const bf16x8*)&Vts[cur][(nt * 16 + lr) * ASTR + quad * 8];
            bf16x8 vb1 = *(const bf16x8*)&Vts[cur][(nt * 16 + lr) * ASTR + 32 + quad * 8];
            #pragma unroll
            for (int rg = 0; rg < 2; ++rg) {
                acc[rg][nt] = __builtin_amdgcn_mfma_f32_16x16x32_bf16(pa[rg][0], vb0, acc[rg][nt], 0, 0, 0);
                acc[rg][nt] = __builtin_amdgcn_mfma_f32_16x16x32_bf16(pa[rg][1], vb1, acc[rg][nt], 0, 0, 0);
            }
        }

        if (more) {   // write next tile into the other buffer (no reader yet)
            *(uint4*)&Ks[cur ^ 1][sr * ASTR + sc]      = kr0;
            *(uint4*)&Ks[cur ^ 1][sr * ASTR + sc + 8]  = kr1;
            *(uint4*)&Vts[cur ^ 1][sr * ASTR + sc]     = vr0;
            *(uint4*)&Vts[cur ^ 1][sr * ASTR + sc + 8] = vr1;
        }
        __syncthreads();   // all reads of buf[cur] done; buf[cur^1] populated
    }

    // epilogue
    #pragma unroll
    for (int rg = 0; rg < 2; ++rg) {
        #pragma unroll
        for (int r = 0; r < 4; ++r) {
            float l = l_loc[rg][r];
            #pragma unroll
            for (int off = 1; off < 16; off <<= 1) l += __shfl_xor(l, off);
            const float invl = (l > 0.f) ? (1.0f / l) : 0.f;
            const int qrow = wave * 32 + rg * 16 + quad * 4 + r;
            #pragma unroll
            for (int nt = 0; nt < 4; ++nt) {
                ctx[(size_t)(b * T_ + qs + qrow) * D_ + hh * DH + nt * 16 + lr] =
                    f2bf(acc[rg][nt][r] * invl);
            }
        }
    }
}

// ---------------------------------------------------------------- launch
extern "C" void kernel_launch(void* const* d_in, const int* in_sizes, int n_in,
                              void* d_out, int out_size, void* d_ws, size_t ws_size,
                              hipStream_t stream) {
    // ws (64 MiB): [h:16MB][q:16MB][k:16MB][vt:16MB]
    // Wq/Wk/Wv transposed into d_out scratch (dead until final GEMM);
    // Wo transposed into q buffer after attention (q dead by then).
    u16* h = (u16*)d_ws;
    const size_t MD = (size_t)M_ * D_;
    const size_t WD = (size_t)D_ * D_;
    u16* q  = h + MD;
    u16* vt = q + 2 * MD;          // k = q + MD (contiguous with q)
    u16* wtq = (u16*)d_out;        // |wtk|wtv contiguous (3 x 2MB)
    u16* wto = q;

    ln_kernel<<<M_, 256, 0, stream>>>(d_in[0], d_in[1], d_in[2], h);

    dim3 wgrid(D_ / 64, D_ / 64);
    wconv_kernel<<<wgrid, 256, 0, stream>>>(d_in[3], wtq);
    wconv_kernel<<<wgrid, 256, 0, stream>>>(d_in[5], wtq + WD);
    wconv_kernel<<<wgrid, 256, 0, stream>>>(d_in[7], wtq + 2 * WD);

    gemmqkv_kernel<<<dim3(3 * D_ / 128, M_ / 128), 256, 0, stream>>>(
        h, wtq, d_in[4], d_in[6], d_in[8], q);

    attn_kernel<<<dim3(T_ / 128, NB * H_), 256, 0, stream>>>(
        q, q + MD, vt, d_in[13], h);

    wconv_kernel<<<wgrid, 256, 0, stream>>>(d_in[9], wto);
    gemm128_kernel<<<dim3(D_ / 128, M_ / 128), 256, 0, stream>>>(
        h, wto, d_in[9], d_in[10], d_out);
}